// Round 1
// baseline (691.196 us; speedup 1.0000x reference)
//
#include <hip/hip_runtime.h>

// Sub-pixel 5x5 conv, 8 weight sets selected by (oh%4, ow%2).
// fea[b,co,oh,ow] = bias[s,co] + sum_{ci,kh,kw} x[b,ci,oh+kh-2,ow+kw-2] * w[s,co,ci,kh,kw]
//   with s = 2*(oh%4) + (ow%2), zero padding outside [0,720)x[0,1280).
//
// Kernel 1: transpose weights [8][64][3][5][5] -> [8][75][64] in d_ws so that
//           16 consecutive co for a fixed (s,ci,kh,kw) are one s_load_dwordx16.
// Kernel 2: block = (b, r, 4 output rows, 64 output cols), 256 threads.
//           wave -> co block of 16 (block/wave-uniform => weights via SGPR),
//           lane -> (row il 0..3) x (pixel group pg 0..15, 4 consecutive ow).
//           x tile (3 ci x 17 rows x 68 cols) staged in LDS.

__global__ void wtrans_kernel(const float* __restrict__ w, float* __restrict__ wt) {
    int o = blockIdx.x * 256 + threadIdx.x;
    if (o >= 8 * 75 * 64) return;
    int co = o & 63;
    int e  = (o >> 6) % 75;
    int s  = o / (64 * 75);
    wt[o] = w[(s * 64 + co) * 75 + e];
}

__global__ __launch_bounds__(256)
void conv8_kernel(const float* __restrict__ x, const float* __restrict__ wt,
                  const float* __restrict__ bias, float* __restrict__ out) {
    const int b   = blockIdx.z >> 2;
    const int r   = blockIdx.z & 3;
    const int i0  = blockIdx.y * 4;     // 4 output rows (stride-4 family r)
    const int ow0 = blockIdx.x * 64;    // 64 output cols

    const int tid  = threadIdx.x;
    const int lane = tid & 63;
    const int wv   = __builtin_amdgcn_readfirstlane(tid >> 6); // 0..3 co-block
    const int pg   = lane & 15;   // pixel group: 4 consecutive ow
    const int il   = lane >> 4;   // which of the 4 output rows

    __shared__ float xs[3][17][68];   // 13872 B

    // ---- stage x tile (rows 4*i0+r-2 .. +16, cols ow0-2 .. +67) ----
    const int row_base = 4 * i0 + r - 2;
    const int col_base = ow0 - 2;
    #pragma unroll 1
    for (int idx = tid; idx < 3 * 17 * 68; idx += 256) {
        int u  = idx % 68;
        int tt = (idx / 68) % 17;
        int ci = idx / (17 * 68);
        int gr = row_base + tt, gc = col_base + u;
        float v = 0.f;
        if ((unsigned)gr < 720u && (unsigned)gc < 1280u)
            v = x[((b * 3 + ci) * 720 + gr) * 1280 + gc];
        ((float*)xs)[idx] = v;
    }
    __syncthreads();

    const int cobase = wv * 16;
    const float* __restrict__ w0 = wt + (2 * r    ) * 75 * 64 + cobase; // c=0 set
    const float* __restrict__ w1 = wt + (2 * r + 1) * 75 * 64 + cobase; // c=1 set

    float acc[16][4];
    #pragma unroll
    for (int cc = 0; cc < 16; ++cc) {
        float b0 = bias[(2 * r    ) * 64 + cobase + cc];
        float b1 = bias[(2 * r + 1) * 64 + cobase + cc];
        acc[cc][0] = b0; acc[cc][1] = b1; acc[cc][2] = b0; acc[cc][3] = b1;
    }

    #pragma unroll 1
    for (int ci = 0; ci < 3; ++ci) {
        #pragma unroll 1
        for (int kh = 0; kh < 5; ++kh) {
            const float* xrow = &xs[ci][4 * il + kh][4 * pg];
            float xr[8];
            *(float4*)(&xr[0]) = *(const float4*)(xrow);
            *(float4*)(&xr[4]) = *(const float4*)(xrow + 4);
            const int ebase = (ci * 5 + kh) * 5;
            #pragma unroll
            for (int kw = 0; kw < 5; ++kw) {
                const float4* wp0 = (const float4*)(w0 + (ebase + kw) * 64);
                const float4* wp1 = (const float4*)(w1 + (ebase + kw) * 64);
                float wa[16], wb[16];
                *(float4*)&wa[0]  = wp0[0]; *(float4*)&wa[4]  = wp0[1];
                *(float4*)&wa[8]  = wp0[2]; *(float4*)&wa[12] = wp0[3];
                *(float4*)&wb[0]  = wp1[0]; *(float4*)&wb[4]  = wp1[1];
                *(float4*)&wb[8]  = wp1[2]; *(float4*)&wb[12] = wp1[3];
                #pragma unroll
                for (int cc = 0; cc < 16; ++cc) {
                    // q = 0..3 -> parity q&1 selects weight set (ow0,4*pg even)
                    acc[cc][0] = fmaf(xr[kw + 0], wa[cc], acc[cc][0]);
                    acc[cc][1] = fmaf(xr[kw + 1], wb[cc], acc[cc][1]);
                    acc[cc][2] = fmaf(xr[kw + 2], wa[cc], acc[cc][2]);
                    acc[cc][3] = fmaf(xr[kw + 3], wb[cc], acc[cc][3]);
                }
            }
        }
    }

    const int oh = 4 * (i0 + il) + r;
    float* op = out + (((size_t)(b * 64 + cobase) * 720 + oh) * 1280) + ow0 + 4 * pg;
    #pragma unroll
    for (int cc = 0; cc < 16; ++cc) {
        *(float4*)(op) = *(float4*)(&acc[cc][0]);
        op += 720 * 1280;
    }
}

extern "C" void kernel_launch(void* const* d_in, const int* in_sizes, int n_in,
                              void* d_out, int out_size, void* d_ws, size_t ws_size,
                              hipStream_t stream) {
    const float* x    = (const float*)d_in[0];
    const float* w    = (const float*)d_in[1];
    const float* bias = (const float*)d_in[2];
    float* out = (float*)d_out;
    float* wt  = (float*)d_ws;   // 8*75*64 floats = 153.6 KB

    wtrans_kernel<<<dim3(150), dim3(256), 0, stream>>>(w, wt);

    dim3 grid(1280 / 64, 720 / 16, 8);   // (ow tiles, i tiles, b*4 + r)
    conv8_kernel<<<grid, dim3(256), 0, stream>>>(x, wt, bias, out);
}